// Round 11
// baseline (449.457 us; speedup 1.0000x reference)
//
#include <hip/hip_runtime.h>
#include <hip/hip_bf16.h>

#define LRELU(a) ((a) >= 0.0f ? (a) : 0.2f * (a))

typedef __attribute__((ext_vector_type(8))) _Float16 f16x8;
typedef __attribute__((ext_vector_type(4))) _Float16 f16x4;
typedef __attribute__((ext_vector_type(4))) float f32x4;

// ---------------- W1[256][256] and W2[256][64] fp32 -> fp16 transposed, one launch ----------------
__global__ __launch_bounds__(256) void cvt_w_both(const float* __restrict__ W1,
                                                  const float* __restrict__ W2,
                                                  _Float16* __restrict__ T1,
                                                  _Float16* __restrict__ T2) {
    int t = blockIdx.x * 256 + threadIdx.x;
    if (t < 65536) {
        int k = t >> 8, n = t & 255;
        T1[n * 256 + k] = (_Float16)W1[t];
    } else {
        int u = t - 65536;
        if (u < 16384) {
            int k = u >> 6, n = u & 63;
            T2[n * 256 + k] = (_Float16)W2[u];
        }
    }
}

// ---------------- GEMM1 (fp16 MFMA, reg-staged pipeline): h1 = x @ W1, tile 128x256 ----------------
__global__ __launch_bounds__(512) void gemm1_mfma(
    const float* __restrict__ A,
    const _Float16* __restrict__ BT,
    const float* __restrict__ attS, const float* __restrict__ attD,
    _Float16* __restrict__ C, float* __restrict__ a_src, float* __restrict__ a_dst,
    int M) {
    const int K = 256;
    __shared__ _Float16 sAs[128][40];
    __shared__ _Float16 sBs[256][40];
    int tid = threadIdx.x;
    int m0 = blockIdx.y * 128;
    int wid = tid >> 6, lane = tid & 63;
    int wm = (wid >> 2) * 64, wn = (wid & 3) * 64;
    int lr = lane & 15, lg = lane >> 4;

    // staging geometry
    int rA = tid >> 2, sA8 = (tid & 3) * 8;          // A: 128 rows x 32k, one f16x8 slot each
    int growA = m0 + rA;
    bool mok = growA < M;
    const float* Ap = A + (size_t)growA * K + sA8;
    int rB0 = tid >> 2, rB1 = rB0 + 128, sB8 = (tid & 3) * 8;
    const _Float16* Bp0 = BT + (size_t)rB0 * K + sB8;
    const _Float16* Bp1 = BT + (size_t)rB1 * K + sB8;

    f32x4 acc[4][4];
    #pragma unroll
    for (int i = 0; i < 4; ++i)
        #pragma unroll
        for (int j = 0; j < 4; ++j)
            acc[i][j] = (f32x4){0.f, 0.f, 0.f, 0.f};

    float4 pa0 = make_float4(0.f, 0.f, 0.f, 0.f), pa1 = pa0;
    f16x8 pb0, pb1;
    if (mok) {
        pa0 = *(const float4*)(Ap + 0);
        pa1 = *(const float4*)(Ap + 4);
    }
    pb0 = *(const f16x8*)Bp0;
    pb1 = *(const f16x8*)Bp1;

    for (int k0 = 0; k0 < K; k0 += 32) {
        {   // stage current regs -> LDS
            f16x8 hv;
            hv[0] = (_Float16)pa0.x; hv[1] = (_Float16)pa0.y;
            hv[2] = (_Float16)pa0.z; hv[3] = (_Float16)pa0.w;
            hv[4] = (_Float16)pa1.x; hv[5] = (_Float16)pa1.y;
            hv[6] = (_Float16)pa1.z; hv[7] = (_Float16)pa1.w;
            *(f16x8*)&sAs[rA][sA8] = hv;
            *(f16x8*)&sBs[rB0][sB8] = pb0;
            *(f16x8*)&sBs[rB1][sB8] = pb1;
        }
        __syncthreads();
        if (k0 + 32 < K) {  // issue next tile's loads; latency hides under MFMA
            int ko = k0 + 32;
            if (mok) {
                pa0 = *(const float4*)(Ap + ko + 0);
                pa1 = *(const float4*)(Ap + ko + 4);
            }
            pb0 = *(const f16x8*)(Bp0 + ko);
            pb1 = *(const f16x8*)(Bp1 + ko);
        }
        f16x8 bfr[4];
        #pragma unroll
        for (int i = 0; i < 4; ++i)
            bfr[i] = *(const f16x8*)&sBs[wn + i * 16 + lr][lg * 8];
        #pragma unroll
        for (int mi = 0; mi < 4; ++mi) {
            f16x8 av = *(const f16x8*)&sAs[wm + mi * 16 + lr][lg * 8];
            #pragma unroll
            for (int ni = 0; ni < 4; ++ni)
                acc[mi][ni] = __builtin_amdgcn_mfma_f32_16x16x32_f16(av, bfr[ni], acc[mi][ni], 0, 0, 0);
        }
        __syncthreads();
    }

    float asv[4], adv[4];
    #pragma unroll
    for (int ni = 0; ni < 4; ++ni) {
        int col = wn + ni * 16 + lr;
        asv[ni] = attS[col];
        adv[ni] = attD[col];
    }
    int head0 = wn >> 5;
    #pragma unroll
    for (int mi = 0; mi < 4; ++mi) {
        #pragma unroll
        for (int r = 0; r < 4; ++r) {
            int row = m0 + wm + mi * 16 + lg * 4 + r;
            float v0 = acc[mi][0][r], v1 = acc[mi][1][r];
            float v2 = acc[mi][2][r], v3 = acc[mi][3][r];
            float ps0 = v0 * asv[0] + v1 * asv[1], pd0 = v0 * adv[0] + v1 * adv[1];
            float ps1 = v2 * asv[2] + v3 * asv[3], pd1 = v2 * adv[2] + v3 * adv[3];
            #pragma unroll
            for (int msk = 8; msk >= 1; msk >>= 1) {
                ps0 += __shfl_xor(ps0, msk); pd0 += __shfl_xor(pd0, msk);
                ps1 += __shfl_xor(ps1, msk); pd1 += __shfl_xor(pd1, msk);
            }
            if (row < M) {
                C[(size_t)row * 256 + wn +  0 + lr] = (_Float16)v0;
                C[(size_t)row * 256 + wn + 16 + lr] = (_Float16)v1;
                C[(size_t)row * 256 + wn + 32 + lr] = (_Float16)v2;
                C[(size_t)row * 256 + wn + 48 + lr] = (_Float16)v3;
                if (lr == 0) {
                    a_src[(size_t)row * 8 + head0]     = ps0;
                    a_dst[(size_t)row * 8 + head0]     = pd0;
                    a_src[(size_t)row * 8 + head0 + 1] = ps1;
                    a_dst[(size_t)row * 8 + head0 + 1] = pd1;
                }
            }
        }
    }
}

// ---------------- GEMM2 (fp16 MFMA, reg-staged pipeline): h2 = out1 @ W2, tile 128x64 ----------------
__global__ __launch_bounds__(256) void gemm2_mfma(
    const _Float16* __restrict__ A,
    const _Float16* __restrict__ BT,
    const float* __restrict__ attS, const float* __restrict__ attD,
    _Float16* __restrict__ C, float* __restrict__ a_src, float* __restrict__ a_dst,
    int M) {
    const int K = 256;
    __shared__ _Float16 sAs[128][40];
    __shared__ _Float16 sBs[64][40];
    int tid = threadIdx.x;
    int m0 = blockIdx.y * 128;
    int wid = tid >> 6, lane = tid & 63;
    int wm = wid * 32;
    int lr = lane & 15, lg = lane >> 4;

    int rA0 = tid >> 2, rA1 = rA0 + 64, seg8 = (tid & 3) * 8;
    bool mok0 = m0 + rA0 < M, mok1 = m0 + rA1 < M;
    const _Float16* Ap0 = A + (size_t)(m0 + rA0) * K + seg8;
    const _Float16* Ap1 = A + (size_t)(m0 + rA1) * K + seg8;
    const _Float16* Bp = BT + (size_t)(tid >> 2) * K + seg8;

    f32x4 acc[2][4];
    #pragma unroll
    for (int i = 0; i < 2; ++i)
        #pragma unroll
        for (int j = 0; j < 4; ++j)
            acc[i][j] = (f32x4){0.f, 0.f, 0.f, 0.f};

    f16x8 pa0 = {0,0,0,0,0,0,0,0}, pa1 = pa0, pb;
    if (mok0) pa0 = *(const f16x8*)Ap0;
    if (mok1) pa1 = *(const f16x8*)Ap1;
    pb = *(const f16x8*)Bp;

    for (int k0 = 0; k0 < K; k0 += 32) {
        *(f16x8*)&sAs[rA0][seg8] = pa0;
        *(f16x8*)&sAs[rA1][seg8] = pa1;
        *(f16x8*)&sBs[tid >> 2][seg8] = pb;
        __syncthreads();
        if (k0 + 32 < K) {
            int ko = k0 + 32;
            if (mok0) pa0 = *(const f16x8*)(Ap0 + ko);
            if (mok1) pa1 = *(const f16x8*)(Ap1 + ko);
            pb = *(const f16x8*)(Bp + ko);
        }
        f16x8 bfr[4];
        #pragma unroll
        for (int i = 0; i < 4; ++i)
            bfr[i] = *(const f16x8*)&sBs[i * 16 + lr][lg * 8];
        #pragma unroll
        for (int mi = 0; mi < 2; ++mi) {
            f16x8 av = *(const f16x8*)&sAs[wm + mi * 16 + lr][lg * 8];
            #pragma unroll
            for (int ni = 0; ni < 4; ++ni)
                acc[mi][ni] = __builtin_amdgcn_mfma_f32_16x16x32_f16(av, bfr[ni], acc[mi][ni], 0, 0, 0);
        }
        __syncthreads();
    }

    float asv[4], adv[4];
    #pragma unroll
    for (int ni = 0; ni < 4; ++ni) {
        asv[ni] = attS[ni * 16 + lr];
        adv[ni] = attD[ni * 16 + lr];
    }
    #pragma unroll
    for (int mi = 0; mi < 2; ++mi) {
        #pragma unroll
        for (int r = 0; r < 4; ++r) {
            int row = m0 + wm + mi * 16 + lg * 4 + r;
            float ps = 0.f, pd = 0.f;
            #pragma unroll
            for (int ni = 0; ni < 4; ++ni) {
                float v = acc[mi][ni][r];
                ps += v * asv[ni];
                pd += v * adv[ni];
            }
            #pragma unroll
            for (int msk = 8; msk >= 1; msk >>= 1) {
                ps += __shfl_xor(ps, msk);
                pd += __shfl_xor(pd, msk);
            }
            if (row < M) {
                #pragma unroll
                for (int ni = 0; ni < 4; ++ni)
                    C[(size_t)row * 64 + ni * 16 + lr] = (_Float16)acc[mi][ni][r];
                if (lr == 0) { a_src[row] = ps; a_dst[row] = pd; }
            }
        }
    }
}

// ---------------- CSR build: ordered rowptr (3-kernel scan), atomic-free scatter ----------------
__global__ __launch_bounds__(256) void hist_dst(const int* __restrict__ dst, unsigned* __restrict__ cnt,
                                                int* __restrict__ pos, int E) {
    int e = blockIdx.x * 256 + threadIdx.x;
    if (e < E) pos[e] = (int)atomicAdd(&cnt[dst[e]], 1u);
}

__global__ __launch_bounds__(256) void scan_partial(const unsigned* __restrict__ cnt,
                                                    int* __restrict__ rowptr,
                                                    unsigned* __restrict__ bsum, int n) {
    __shared__ unsigned s[256];
    int i = blockIdx.x * 256 + threadIdx.x;
    unsigned v = (i < n) ? cnt[i] : 0u;
    s[threadIdx.x] = v;
    __syncthreads();
    #pragma unroll
    for (int off = 1; off < 256; off <<= 1) {
        unsigned t = (threadIdx.x >= off) ? s[threadIdx.x - off] : 0u;
        __syncthreads();
        s[threadIdx.x] += t;
        __syncthreads();
    }
    if (i < n) rowptr[i + 1] = (int)s[threadIdx.x];
    if (threadIdx.x == 255) bsum[blockIdx.x] = s[255];
}

__global__ __launch_bounds__(512) void scan_bsum(unsigned* __restrict__ bsum, int nb) {
    __shared__ unsigned s[512];
    int t = threadIdx.x;
    s[t] = (t < nb) ? bsum[t] : 0u;
    __syncthreads();
    #pragma unroll
    for (int off = 1; off < 512; off <<= 1) {
        unsigned v = (t >= off) ? s[t - off] : 0u;
        __syncthreads();
        s[t] += v;
        __syncthreads();
    }
    unsigned ex = (t == 0) ? 0u : s[t - 1];
    if (t < nb) bsum[t] = ex;
}

__global__ __launch_bounds__(256) void scan_add(int* __restrict__ rowptr, const unsigned* __restrict__ boff, int n) {
    int i = blockIdx.x * 256 + threadIdx.x;
    if (i < n) rowptr[i + 1] += (int)boff[blockIdx.x];
    if (blockIdx.x == 0 && threadIdx.x == 0) rowptr[0] = 0;
}

__global__ __launch_bounds__(256) void scatter_srcs(const int* __restrict__ src, const int* __restrict__ dst,
                                                    const int* __restrict__ rowptr, const int* __restrict__ pos,
                                                    int* __restrict__ srcs, int E) {
    int e = blockIdx.x * 256 + threadIdx.x;
    if (e >= E) return;
    srcs[rowptr[dst[e]] + pos[e]] = src[e];
}

// ---------------- Layer-1 aggregation: 16-deep pipelined gathers ----------------
__global__ __launch_bounds__(256) void agg1(const int* __restrict__ srcs,
                                            const int* __restrict__ begA,
                                            const int* __restrict__ endB,
                                            const float* __restrict__ a_src,
                                            const float* __restrict__ a_dst,
                                            const _Float16* __restrict__ h1,
                                            _Float16* __restrict__ o1, int N) {
    int wid = threadIdx.x >> 6;
    int lane = threadIdx.x & 63;
    int d = blockIdx.x * 4 + wid;
    if (d >= N) return;
    int beg = begA[d], end = endB[d];
    int e8 = lane & 7;   // edge slot within half-batch
    int hd = lane >> 3;  // head (for weight calc); my 4 channels = lane*4..
    int base = lane & 56;
    float adst = a_dst[(size_t)d * 8 + hd];
    const char* h1b = (const char*)h1;
    const char* asb = (const char*)a_src;
    unsigned loff = (unsigned)(lane << 3);  // my 8-byte slice within a 512 B row

    float4 acc = make_float4(0.f, 0.f, 0.f, 0.f);
    float wsum = 0.0f;
    for (int j0 = beg; j0 < end; j0 += 16) {
        int nb = end - j0;  // wave-uniform
        int sa = 0, sc = 0; float wa = 0.f, wb = 0.f;
        if (e8 < nb) {
            sa = srcs[j0 + e8];
            float a = *(const float*)(asb + (((unsigned)sa << 5) + ((unsigned)hd << 2))) + adst;
            wa = __expf(LRELU(a));
        }
        if (e8 + 8 < nb) {
            sc = srcs[j0 + e8 + 8];
            float a = *(const float*)(asb + (((unsigned)sc << 5) + ((unsigned)hd << 2))) + adst;
            wb = __expf(LRELU(a));
        }
        wsum += wa + wb;
        if (nb >= 16) {
            float at[16]; unsigned sb[16];
            #pragma unroll
            for (int t = 0; t < 8; ++t) {
                at[t]     = __shfl(wa, base | t);
                sb[t]     = ((unsigned)__shfl(sa, base | t)) << 9;
                at[8 + t] = __shfl(wb, base | t);
                sb[8 + t] = ((unsigned)__shfl(sc, base | t)) << 9;
            }
            f16x4 hv[16];
            #pragma unroll
            for (int t = 0; t < 16; ++t)
                hv[t] = *(const f16x4*)(h1b + (sb[t] + loff));
            #pragma unroll
            for (int t = 0; t < 16; ++t) {
                acc.x += (float)hv[t][0] * at[t];
                acc.y += (float)hv[t][1] * at[t];
                acc.z += (float)hv[t][2] * at[t];
                acc.w += (float)hv[t][3] * at[t];
            }
        } else {
            int n1 = nb < 8 ? nb : 8;
            for (int t = 0; t < n1; ++t) {
                float at = __shfl(wa, base | t);
                unsigned sb = ((unsigned)__shfl(sa, base | t)) << 9;
                f16x4 hq = *(const f16x4*)(h1b + (sb + loff));
                acc.x += (float)hq[0] * at;
                acc.y += (float)hq[1] * at;
                acc.z += (float)hq[2] * at;
                acc.w += (float)hq[3] * at;
            }
            for (int t = 8; t < nb; ++t) {
                float at = __shfl(wb, base | (t - 8));
                unsigned sb = ((unsigned)__shfl(sc, base | (t - 8))) << 9;
                f16x4 hq = *(const f16x4*)(h1b + (sb + loff));
                acc.x += (float)hq[0] * at;
                acc.y += (float)hq[1] * at;
                acc.z += (float)hq[2] * at;
                acc.w += (float)hq[3] * at;
            }
        }
    }
    // sum weights across the 8 edge-slots of my head
    wsum += __shfl_xor(wsum, 1);
    wsum += __shfl_xor(wsum, 2);
    wsum += __shfl_xor(wsum, 4);
    float rw = 1.0f / (wsum + 1e-16f);
    acc.x *= rw; acc.y *= rw; acc.z *= rw; acc.w *= rw;
    // fused ELU + fp16 store
    acc.x = acc.x > 0.0f ? acc.x : expm1f(acc.x);
    acc.y = acc.y > 0.0f ? acc.y : expm1f(acc.y);
    acc.z = acc.z > 0.0f ? acc.z : expm1f(acc.z);
    acc.w = acc.w > 0.0f ? acc.w : expm1f(acc.w);
    f16x4 hh;
    hh[0] = (_Float16)acc.x;
    hh[1] = (_Float16)acc.y;
    hh[2] = (_Float16)acc.z;
    hh[3] = (_Float16)acc.w;
    *(f16x4*)(o1 + (size_t)d * 256 + lane * 4) = hh;
}

// ---------------- Layer-2 aggregation: batched loads (up to 16 in flight) ----------------
__global__ __launch_bounds__(256) void agg2(const int* __restrict__ srcs,
                                            const int* __restrict__ begA,
                                            const int* __restrict__ endB,
                                            const float* __restrict__ a_src,
                                            const float* __restrict__ a_dst,
                                            const _Float16* __restrict__ h2,
                                            float* __restrict__ out, int N) {
    int wid = threadIdx.x >> 6;
    int lane = threadIdx.x & 63;
    int d = blockIdx.x * 4 + wid;
    if (d >= N) return;
    int beg = begA[d], end = endB[d];
    float adst = a_dst[d];
    const char* h2b = (const char*)h2;
    int grp = lane >> 4;   // which edge of the quad I gather for
    int cid = lane & 15;   // my 4 channels: cid*4 .. cid*4+3
    unsigned coff = (unsigned)(cid << 3);

    float4 acc = make_float4(0.f, 0.f, 0.f, 0.f);
    float wsum = 0.0f;
    for (int j0 = beg; j0 < end; j0 += 64) {
        int nb = end - j0; if (nb > 64) nb = 64;
        int s2 = 0; float w = 0.f;
        if (lane < nb) {
            s2 = srcs[j0 + lane];
            float a = LRELU(a_src[s2] + adst);
            w = __expf(a);
        }
        wsum += w;
        int tmax = (nb + 3) >> 2;  // wave-uniform
        float at[16]; unsigned sb[16];
        #pragma unroll
        for (int t = 0; t < 16; ++t) {
            if (t < tmax) {
                int ei = 4 * t + grp;
                at[t] = __shfl(w, ei);       // slots >= nb carry w=0 -> harmless
                sb[t] = ((unsigned)__shfl(s2, ei)) << 7;
            }
        }
        f16x4 hv[16];
        #pragma unroll
        for (int t = 0; t < 16; ++t)
            if (t < tmax) hv[t] = *(const f16x4*)(h2b + (sb[t] + coff));
        #pragma unroll
        for (int t = 0; t < 16; ++t) {
            if (t < tmax) {
                acc.x += (float)hv[t][0] * at[t];
                acc.y += (float)hv[t][1] * at[t];
                acc.z += (float)hv[t][2] * at[t];
                acc.w += (float)hv[t][3] * at[t];
            }
        }
    }
    #pragma unroll
    for (int mask = 16; mask <= 32; mask <<= 1) {
        acc.x += __shfl_xor(acc.x, mask);
        acc.y += __shfl_xor(acc.y, mask);
        acc.z += __shfl_xor(acc.z, mask);
        acc.w += __shfl_xor(acc.w, mask);
    }
    #pragma unroll
    for (int mask = 1; mask < 64; mask <<= 1)
        wsum += __shfl_xor(wsum, mask);
    float rw = 1.0f / (wsum + 1e-16f);
    if (lane < 16) {
        float4 o = make_float4(acc.x * rw, acc.y * rw, acc.z * rw, acc.w * rw);
        *(float4*)(out + (size_t)d * 64 + cid * 4) = o;
    }
}

extern "C" void kernel_launch(void* const* d_in, const int* in_sizes, int n_in,
                              void* d_out, int out_size, void* d_ws, size_t ws_size,
                              hipStream_t stream) {
    const float* x        = (const float*)d_in[0];
    const float* W1       = (const float*)d_in[1];
    const float* att_src1 = (const float*)d_in[2];
    const float* att_dst1 = (const float*)d_in[3];
    const float* W2       = (const float*)d_in[4];
    const float* att_src2 = (const float*)d_in[5];
    const float* att_dst2 = (const float*)d_in[6];
    const int*   ei       = (const int*)d_in[7];

    int N = in_sizes[0] / 256;
    int E = in_sizes[7] / 2;
    const int* src = ei;
    const int* dst = ei + E;

    _Float16* out1 = (_Float16*)d_ws;                        // [N*256] fp16
    _Float16* h1f  = out1 + (size_t)N * 256;                 // [N*256] fp16 -> reused as h2
    float* a_src1v = (float*)(h1f + (size_t)N * 256);        // [N,8]
    float* a_dst1v = a_src1v + (size_t)N * 8;                // [N,8]
    float* a_src2v = a_dst1v + (size_t)N * 8;                // [N]
    float* a_dst2v = a_src2v + N;                            // [N]
    int*   rowptr  = (int*)(a_dst2v + N);                    // [N+1]
    unsigned* cnt  = (unsigned*)(rowptr + N + 1);            // [N]
    unsigned* bsum = cnt + N;                                // [512]
    int*   pos     = (int*)(bsum + 512);                     // [E]
    int*   srcs    = pos + E;                                // [E]
    _Float16* w1t  = (_Float16*)(srcs + E);                  // [256*256]
    _Float16* w2t  = w1t + 65536;                            // [64*256]

    _Float16* h2f = h1f;  // h1 dead after agg1

    float* outf = (float*)d_out;
    int nb = (N + 255) / 256;  // 391 <= 512

    // ---- CSR build (ordered rowptr; atomic-free scatter) ----
    hipMemsetAsync(cnt, 0, (size_t)N * sizeof(unsigned), stream);
    hist_dst<<<(E + 255) / 256, 256, 0, stream>>>(dst, cnt, pos, E);
    scan_partial<<<nb, 256, 0, stream>>>(cnt, rowptr, bsum, N);
    scan_bsum<<<1, 512, 0, stream>>>(bsum, nb);
    scan_add<<<nb, 256, 0, stream>>>(rowptr, bsum, N);
    scatter_srcs<<<(E + 255) / 256, 256, 0, stream>>>(src, dst, rowptr, pos, srcs, E);

    // ---- weight conversion (single launch) ----
    cvt_w_both<<<(65536 + 16384 + 255) / 256, 256, 0, stream>>>(W1, W2, w1t, w2t);

    // ---- layer 1 ----
    gemm1_mfma<<<dim3(1, (N + 127) / 128), 512, 0, stream>>>(x, w1t,
                                                             att_src1, att_dst1,
                                                             h1f, a_src1v, a_dst1v, N);
    agg1<<<(N + 3) / 4, 256, 0, stream>>>(srcs, rowptr, rowptr + 1, a_src1v, a_dst1v, h1f, out1, N);

    // ---- layer 2 ----
    gemm2_mfma<<<dim3(1, (N + 127) / 128), 256, 0, stream>>>(out1, w2t,
                                                             att_src2, att_dst2,
                                                             h2f, a_src2v, a_dst2v, N);
    agg2<<<(N + 3) / 4, 256, 0, stream>>>(srcs, rowptr, rowptr + 1, a_src2v, a_dst2v, h2f, outf, N);
}

// Round 12
// 388.843 us; speedup vs baseline: 1.1559x; 1.1559x over previous
//
#include <hip/hip_runtime.h>
#include <hip/hip_bf16.h>

#define LRELU(a) ((a) >= 0.0f ? (a) : 0.2f * (a))

typedef __attribute__((ext_vector_type(8))) _Float16 f16x8;
typedef __attribute__((ext_vector_type(4))) _Float16 f16x4;
typedef __attribute__((ext_vector_type(4))) float f32x4;

// ---------------- W1[256][256] and W2[256][64] fp32 -> fp16 transposed, one launch ----------------
__global__ __launch_bounds__(256) void cvt_w_both(const float* __restrict__ W1,
                                                  const float* __restrict__ W2,
                                                  _Float16* __restrict__ T1,
                                                  _Float16* __restrict__ T2) {
    int t = blockIdx.x * 256 + threadIdx.x;
    if (t < 65536) {
        int k = t >> 8, n = t & 255;
        T1[n * 256 + k] = (_Float16)W1[t];
    } else {
        int u = t - 65536;
        if (u < 16384) {
            int k = u >> 6, n = u & 63;
            T2[n * 256 + k] = (_Float16)W2[u];
        }
    }
}

// ---------------- GEMM1 (fp16 MFMA): h1 = x @ W1, tile 128x256, fused att scores ----------------
__global__ __launch_bounds__(512) void gemm1_mfma(
    const float* __restrict__ A,
    const _Float16* __restrict__ BT,
    const float* __restrict__ attS, const float* __restrict__ attD,
    _Float16* __restrict__ C, float* __restrict__ a_src, float* __restrict__ a_dst,
    int M) {
    const int K = 256;
    __shared__ _Float16 sA[128][40];
    __shared__ _Float16 sB[256][40];
    int tid = threadIdx.x;
    int m0 = blockIdx.y * 128;
    int wid = tid >> 6, lane = tid & 63;
    int wm = (wid >> 2) * 64, wn = (wid & 3) * 64;
    int lr = lane & 15, lg = lane >> 4;

    f32x4 acc[4][4];
    #pragma unroll
    for (int i = 0; i < 4; ++i)
        #pragma unroll
        for (int j = 0; j < 4; ++j)
            acc[i][j] = (f32x4){0.f, 0.f, 0.f, 0.f};

    for (int k0 = 0; k0 < K; k0 += 32) {
        {   // A: 128 rows x 32 k fp32 -> fp16
            int row = tid >> 2, seg = tid & 3;
            int grow = m0 + row;
            float4 v0 = make_float4(0.f, 0.f, 0.f, 0.f), v1 = v0;
            if (grow < M) {
                v0 = *(const float4*)&A[(size_t)grow * K + k0 + seg * 8];
                v1 = *(const float4*)&A[(size_t)grow * K + k0 + seg * 8 + 4];
            }
            f16x8 hv;
            hv[0] = (_Float16)v0.x; hv[1] = (_Float16)v0.y;
            hv[2] = (_Float16)v0.z; hv[3] = (_Float16)v0.w;
            hv[4] = (_Float16)v1.x; hv[5] = (_Float16)v1.y;
            hv[6] = (_Float16)v1.z; hv[7] = (_Float16)v1.w;
            *(f16x8*)&sA[row][seg * 8] = hv;
        }
        #pragma unroll
        for (int rnd = 0; rnd < 2; ++rnd) {  // B: 256 rows x 32 k fp16
            int idx = tid + rnd * 512;
            int row = idx >> 2, seg = idx & 3;
            *(f16x8*)&sB[row][seg * 8] = *(const f16x8*)&BT[(size_t)row * K + k0 + seg * 8];
        }
        __syncthreads();
        f16x8 bfr[4];
        #pragma unroll
        for (int i = 0; i < 4; ++i)
            bfr[i] = *(const f16x8*)&sB[wn + i * 16 + lr][lg * 8];
        #pragma unroll
        for (int mi = 0; mi < 4; ++mi) {
            f16x8 av = *(const f16x8*)&sA[wm + mi * 16 + lr][lg * 8];
            #pragma unroll
            for (int ni = 0; ni < 4; ++ni)
                acc[mi][ni] = __builtin_amdgcn_mfma_f32_16x16x32_f16(av, bfr[ni], acc[mi][ni], 0, 0, 0);
        }
        __syncthreads();
    }

    float asv[4], adv[4];
    #pragma unroll
    for (int ni = 0; ni < 4; ++ni) {
        int col = wn + ni * 16 + lr;
        asv[ni] = attS[col];
        adv[ni] = attD[col];
    }
    int head0 = wn >> 5;
    #pragma unroll
    for (int mi = 0; mi < 4; ++mi) {
        #pragma unroll
        for (int r = 0; r < 4; ++r) {
            int row = m0 + wm + mi * 16 + lg * 4 + r;
            float v0 = acc[mi][0][r], v1 = acc[mi][1][r];
            float v2 = acc[mi][2][r], v3 = acc[mi][3][r];
            float ps0 = v0 * asv[0] + v1 * asv[1], pd0 = v0 * adv[0] + v1 * adv[1];
            float ps1 = v2 * asv[2] + v3 * asv[3], pd1 = v2 * adv[2] + v3 * adv[3];
            #pragma unroll
            for (int msk = 8; msk >= 1; msk >>= 1) {
                ps0 += __shfl_xor(ps0, msk); pd0 += __shfl_xor(pd0, msk);
                ps1 += __shfl_xor(ps1, msk); pd1 += __shfl_xor(pd1, msk);
            }
            if (row < M) {
                C[(size_t)row * 256 + wn +  0 + lr] = (_Float16)v0;
                C[(size_t)row * 256 + wn + 16 + lr] = (_Float16)v1;
                C[(size_t)row * 256 + wn + 32 + lr] = (_Float16)v2;
                C[(size_t)row * 256 + wn + 48 + lr] = (_Float16)v3;
                if (lr == 0) {
                    a_src[(size_t)row * 8 + head0]     = ps0;
                    a_dst[(size_t)row * 8 + head0]     = pd0;
                    a_src[(size_t)row * 8 + head0 + 1] = ps1;
                    a_dst[(size_t)row * 8 + head0 + 1] = pd1;
                }
            }
        }
    }
}

// ---------------- GEMM2 (fp16 MFMA): h2 = out1 @ W2, tile 128x64, fused att scores ----------------
__global__ __launch_bounds__(256) void gemm2_mfma(
    const _Float16* __restrict__ A,
    const _Float16* __restrict__ BT,
    const float* __restrict__ attS, const float* __restrict__ attD,
    _Float16* __restrict__ C, float* __restrict__ a_src, float* __restrict__ a_dst,
    int M) {
    const int K = 256;
    __shared__ _Float16 sA[128][40];
    __shared__ _Float16 sB[64][40];
    int tid = threadIdx.x;
    int m0 = blockIdx.y * 128;
    int wid = tid >> 6, lane = tid & 63;
    int wm = wid * 32;
    int lr = lane & 15, lg = lane >> 4;

    f32x4 acc[2][4];
    #pragma unroll
    for (int i = 0; i < 2; ++i)
        #pragma unroll
        for (int j = 0; j < 4; ++j)
            acc[i][j] = (f32x4){0.f, 0.f, 0.f, 0.f};

    for (int k0 = 0; k0 < K; k0 += 32) {
        #pragma unroll
        for (int rnd = 0; rnd < 2; ++rnd) {  // A: 128 rows x 32 k
            int idx = tid + rnd * 256;
            int row = idx >> 2, seg = idx & 3;
            int grow = m0 + row;
            f16x8 va = {0, 0, 0, 0, 0, 0, 0, 0};
            if (grow < M) va = *(const f16x8*)&A[(size_t)grow * K + k0 + seg * 8];
            *(f16x8*)&sA[row][seg * 8] = va;
        }
        {   // B: 64 rows x 32 k
            int row = tid >> 2, seg = tid & 3;
            *(f16x8*)&sB[row][seg * 8] = *(const f16x8*)&BT[(size_t)row * K + k0 + seg * 8];
        }
        __syncthreads();
        f16x8 bfr[4];
        #pragma unroll
        for (int i = 0; i < 4; ++i)
            bfr[i] = *(const f16x8*)&sB[i * 16 + lr][lg * 8];
        #pragma unroll
        for (int mi = 0; mi < 2; ++mi) {
            f16x8 av = *(const f16x8*)&sA[wm + mi * 16 + lr][lg * 8];
            #pragma unroll
            for (int ni = 0; ni < 4; ++ni)
                acc[mi][ni] = __builtin_amdgcn_mfma_f32_16x16x32_f16(av, bfr[ni], acc[mi][ni], 0, 0, 0);
        }
        __syncthreads();
    }

    float asv[4], adv[4];
    #pragma unroll
    for (int ni = 0; ni < 4; ++ni) {
        asv[ni] = attS[ni * 16 + lr];
        adv[ni] = attD[ni * 16 + lr];
    }
    #pragma unroll
    for (int mi = 0; mi < 2; ++mi) {
        #pragma unroll
        for (int r = 0; r < 4; ++r) {
            int row = m0 + wm + mi * 16 + lg * 4 + r;
            float ps = 0.f, pd = 0.f;
            #pragma unroll
            for (int ni = 0; ni < 4; ++ni) {
                float v = acc[mi][ni][r];
                ps += v * asv[ni];
                pd += v * adv[ni];
            }
            #pragma unroll
            for (int msk = 8; msk >= 1; msk >>= 1) {
                ps += __shfl_xor(ps, msk);
                pd += __shfl_xor(pd, msk);
            }
            if (row < M) {
                #pragma unroll
                for (int ni = 0; ni < 4; ++ni)
                    C[(size_t)row * 64 + ni * 16 + lr] = (_Float16)acc[mi][ni][r];
                if (lr == 0) { a_src[row] = ps; a_dst[row] = pd; }
            }
        }
    }
}

// ---------------- CSR build: ordered rowptr (3-kernel scan), atomic-free scatter ----------------
__global__ __launch_bounds__(256) void hist_dst(const int* __restrict__ dst, unsigned* __restrict__ cnt,
                                                int* __restrict__ pos, int E) {
    int e = blockIdx.x * 256 + threadIdx.x;
    if (e < E) pos[e] = (int)atomicAdd(&cnt[dst[e]], 1u);
}

__global__ __launch_bounds__(256) void scan_partial(const unsigned* __restrict__ cnt,
                                                    int* __restrict__ rowptr,
                                                    unsigned* __restrict__ bsum, int n) {
    __shared__ unsigned s[256];
    int i = blockIdx.x * 256 + threadIdx.x;
    unsigned v = (i < n) ? cnt[i] : 0u;
    s[threadIdx.x] = v;
    __syncthreads();
    #pragma unroll
    for (int off = 1; off < 256; off <<= 1) {
        unsigned t = (threadIdx.x >= off) ? s[threadIdx.x - off] : 0u;
        __syncthreads();
        s[threadIdx.x] += t;
        __syncthreads();
    }
    if (i < n) rowptr[i + 1] = (int)s[threadIdx.x];
    if (threadIdx.x == 255) bsum[blockIdx.x] = s[255];
}

__global__ __launch_bounds__(512) void scan_bsum(unsigned* __restrict__ bsum, int nb) {
    __shared__ unsigned s[512];
    int t = threadIdx.x;
    s[t] = (t < nb) ? bsum[t] : 0u;
    __syncthreads();
    #pragma unroll
    for (int off = 1; off < 512; off <<= 1) {
        unsigned v = (t >= off) ? s[t - off] : 0u;
        __syncthreads();
        s[t] += v;
        __syncthreads();
    }
    unsigned ex = (t == 0) ? 0u : s[t - 1];
    if (t < nb) bsum[t] = ex;
}

__global__ __launch_bounds__(256) void scan_add(int* __restrict__ rowptr, const unsigned* __restrict__ boff, int n) {
    int i = blockIdx.x * 256 + threadIdx.x;
    if (i < n) rowptr[i + 1] += (int)boff[blockIdx.x];
    if (blockIdx.x == 0 && threadIdx.x == 0) rowptr[0] = 0;
}

__global__ __launch_bounds__(256) void scatter_srcs(const int* __restrict__ src, const int* __restrict__ dst,
                                                    const int* __restrict__ rowptr, const int* __restrict__ pos,
                                                    int* __restrict__ srcs, int E) {
    int e = blockIdx.x * 256 + threadIdx.x;
    if (e >= E) return;
    srcs[rowptr[dst[e]] + pos[e]] = src[e];
}

// ---------------- Layer-1 aggregation (R8/R10 proven): single pass, batched, pipelined 8x8B gathers ----------------
__global__ __launch_bounds__(256) void agg1(const int* __restrict__ srcs,
                                            const int* __restrict__ begA,
                                            const int* __restrict__ endB,
                                            const float* __restrict__ a_src,
                                            const float* __restrict__ a_dst,
                                            const _Float16* __restrict__ h1,
                                            _Float16* __restrict__ o1, int N) {
    int wid = threadIdx.x >> 6;
    int lane = threadIdx.x & 63;
    int d = blockIdx.x * 4 + wid;
    if (d >= N) return;
    int beg = begA[d], end = endB[d];
    int e8 = lane & 7;   // edge slot within batch
    int hd = lane >> 3;  // head (for weight calc); my 4 channels = lane*4..
    float adst = a_dst[(size_t)d * 8 + hd];
    const char* h1b = (const char*)h1;
    const char* asb = (const char*)a_src;
    unsigned loff = (unsigned)(lane << 3);  // my 8-byte slice within a 512 B row

    float4 acc = make_float4(0.f, 0.f, 0.f, 0.f);
    float wsum = 0.0f;
    for (int j0 = beg; j0 < end; j0 += 8) {
        int nb = end - j0;
        int s2 = 0; float w = 0.f;
        if (e8 < nb) {  // lane computes weight for edge j0+e8, head hd
            s2 = srcs[j0 + e8];
            float a = *(const float*)(asb + (((unsigned)s2 << 5) + ((unsigned)hd << 2))) + adst;
            a = LRELU(a);
            w = __expf(a);
        }
        wsum += w;
        if (nb >= 8) {
            float at[8]; unsigned sb[8];
            #pragma unroll
            for (int t = 0; t < 8; ++t) {
                int sl = (lane & 56) | t;
                at[t] = __shfl(w, sl);
                sb[t] = ((unsigned)__shfl(s2, sl)) << 9;
            }
            f16x4 hv[8];
            #pragma unroll
            for (int t = 0; t < 8; ++t)
                hv[t] = *(const f16x4*)(h1b + (sb[t] + loff));
            #pragma unroll
            for (int t = 0; t < 8; ++t) {
                acc.x += (float)hv[t][0] * at[t];
                acc.y += (float)hv[t][1] * at[t];
                acc.z += (float)hv[t][2] * at[t];
                acc.w += (float)hv[t][3] * at[t];
            }
        } else {
            for (int t = 0; t < nb; ++t) {
                int sl = (lane & 56) | t;
                float at = __shfl(w, sl);
                int s = __shfl(s2, sl);
                f16x4 hq = *(const f16x4*)(h1b + (((unsigned)s << 9) + loff));
                acc.x += (float)hq[0] * at;
                acc.y += (float)hq[1] * at;
                acc.z += (float)hq[2] * at;
                acc.w += (float)hq[3] * at;
            }
        }
    }
    // sum weights across the 8 edge-slots of my head
    wsum += __shfl_xor(wsum, 1);
    wsum += __shfl_xor(wsum, 2);
    wsum += __shfl_xor(wsum, 4);
    float rw = 1.0f / (wsum + 1e-16f);
    acc.x *= rw; acc.y *= rw; acc.z *= rw; acc.w *= rw;
    // fused ELU + fp16 store
    acc.x = acc.x > 0.0f ? acc.x : expm1f(acc.x);
    acc.y = acc.y > 0.0f ? acc.y : expm1f(acc.y);
    acc.z = acc.z > 0.0f ? acc.z : expm1f(acc.z);
    acc.w = acc.w > 0.0f ? acc.w : expm1f(acc.w);
    f16x4 hh;
    hh[0] = (_Float16)acc.x;
    hh[1] = (_Float16)acc.y;
    hh[2] = (_Float16)acc.z;
    hh[3] = (_Float16)acc.w;
    *(f16x4*)(o1 + (size_t)d * 256 + lane * 4) = hh;
}

// ---------------- Layer-2 aggregation (R8/R10 proven): 4 edges/step, 8B loads ----------------
__global__ __launch_bounds__(256) void agg2(const int* __restrict__ srcs,
                                            const int* __restrict__ begA,
                                            const int* __restrict__ endB,
                                            const float* __restrict__ a_src,
                                            const float* __restrict__ a_dst,
                                            const _Float16* __restrict__ h2,
                                            float* __restrict__ out, int N) {
    int wid = threadIdx.x >> 6;
    int lane = threadIdx.x & 63;
    int d = blockIdx.x * 4 + wid;
    if (d >= N) return;
    int beg = begA[d], end = endB[d];
    float adst = a_dst[d];
    const char* h2b = (const char*)h2;
    int grp = lane >> 4;   // which edge of the quad I gather for
    int cid = lane & 15;   // my 4 channels: cid*4 .. cid*4+3

    float4 acc = make_float4(0.f, 0.f, 0.f, 0.f);
    float wsum = 0.0f;
    for (int j0 = beg; j0 < end; j0 += 64) {
        int nb = end - j0; if (nb > 64) nb = 64;
        int s2 = 0; float w = 0.f;
        if (lane < nb) {
            s2 = srcs[j0 + lane];
            float a = LRELU(a_src[s2] + adst);
            w = __expf(a);
        }
        wsum += w;
        int tmax = (nb + 3) >> 2;
        for (int t = 0; t < tmax; ++t) {
            int ei = 4 * t + grp;
            float at = __shfl(w, ei);      // lanes >= nb hold w=0, s2=0 -> harmless
            int s = __shfl(s2, ei);
            f16x4 hv = *(const f16x4*)(h2b + (((unsigned)s << 7) + ((unsigned)cid << 3)));
            acc.x += (float)hv[0] * at;
            acc.y += (float)hv[1] * at;
            acc.z += (float)hv[2] * at;
            acc.w += (float)hv[3] * at;
        }
    }
    #pragma unroll
    for (int mask = 16; mask <= 32; mask <<= 1) {
        acc.x += __shfl_xor(acc.x, mask);
        acc.y += __shfl_xor(acc.y, mask);
        acc.z += __shfl_xor(acc.z, mask);
        acc.w += __shfl_xor(acc.w, mask);
    }
    #pragma unroll
    for (int mask = 1; mask < 64; mask <<= 1)
        wsum += __shfl_xor(wsum, mask);
    float rw = 1.0f / (wsum + 1e-16f);
    if (lane < 16) {
        float4 o = make_float4(acc.x * rw, acc.y * rw, acc.z * rw, acc.w * rw);
        *(float4*)(out + (size_t)d * 64 + cid * 4) = o;
    }
}

extern "C" void kernel_launch(void* const* d_in, const int* in_sizes, int n_in,
                              void* d_out, int out_size, void* d_ws, size_t ws_size,
                              hipStream_t stream) {
    const float* x        = (const float*)d_in[0];
    const float* W1       = (const float*)d_in[1];
    const float* att_src1 = (const float*)d_in[2];
    const float* att_dst1 = (const float*)d_in[3];
    const float* W2       = (const float*)d_in[4];
    const float* att_src2 = (const float*)d_in[5];
    const float* att_dst2 = (const float*)d_in[6];
    const int*   ei       = (const int*)d_in[7];

    int N = in_sizes[0] / 256;
    int E = in_sizes[7] / 2;
    const int* src = ei;
    const int* dst = ei + E;

    _Float16* out1 = (_Float16*)d_ws;                        // [N*256] fp16
    _Float16* h1f  = out1 + (size_t)N * 256;                 // [N*256] fp16 -> reused as h2
    float* a_src1v = (float*)(h1f + (size_t)N * 256);        // [N,8]
    float* a_dst1v = a_src1v + (size_t)N * 8;                // [N,8]
    float* a_src2v = a_dst1v + (size_t)N * 8;                // [N]
    float* a_dst2v = a_src2v + N;                            // [N]
    int*   rowptr  = (int*)(a_dst2v + N);                    // [N+1]
    unsigned* cnt  = (unsigned*)(rowptr + N + 1);            // [N]
    unsigned* bsum = cnt + N;                                // [512]
    int*   pos     = (int*)(bsum + 512);                     // [E]
    int*   srcs    = pos + E;                                // [E]
    _Float16* w1t  = (_Float16*)(srcs + E);                  // [256*256]
    _Float16* w2t  = w1t + 65536;                            // [64*256]

    _Float16* h2f = h1f;  // h1 dead after agg1

    float* outf = (float*)d_out;
    int nb = (N + 255) / 256;  // 391 <= 512

    // ---- CSR build (ordered rowptr; atomic-free scatter) ----
    hipMemsetAsync(cnt, 0, (size_t)N * sizeof(unsigned), stream);
    hist_dst<<<(E + 255) / 256, 256, 0, stream>>>(dst, cnt, pos, E);
    scan_partial<<<nb, 256, 0, stream>>>(cnt, rowptr, bsum, N);
    scan_bsum<<<1, 512, 0, stream>>>(bsum, nb);
    scan_add<<<nb, 256, 0, stream>>>(rowptr, bsum, N);
    scatter_srcs<<<(E + 255) / 256, 256, 0, stream>>>(src, dst, rowptr, pos, srcs, E);

    // ---- weight conversion (single launch) ----
    cvt_w_both<<<(65536 + 16384 + 255) / 256, 256, 0, stream>>>(W1, W2, w1t, w2t);

    // ---- layer 1 ----
    gemm1_mfma<<<dim3(1, (N + 127) / 128), 512, 0, stream>>>(x, w1t,
                                                             att_src1, att_dst1,
                                                             h1f, a_src1v, a_dst1v, N);
    agg1<<<(N + 3) / 4, 256, 0, stream>>>(srcs, rowptr, rowptr + 1, a_src1v, a_dst1v, h1f, out1, N);

    // ---- layer 2 ----
    gemm2_mfma<<<dim3(1, (N + 127) / 128), 256, 0, stream>>>(out1, w2t,
                                                             att_src2, att_dst2,
                                                             h2f, a_src2v, a_dst2v, N);
    agg2<<<(N + 3) / 4, 256, 0, stream>>>(srcs, rowptr, rowptr + 1, a_src2v, a_dst2v, h2f, outf, N);
}